// Round 1
// baseline (469.741 us; speedup 1.0000x reference)
//
#include <hip/hip_runtime.h>

#define NUM_ATOMS 51
#define ROWS_PER_BLOCK 4   // 4 waves of 64 lanes; one wave per row

__global__ __launch_bounds__(256) void c51_bellman_kernel(
    const float* __restrict__ reward,
    const float* __restrict__ probs,
    float* __restrict__ out,
    int bs)
{
    const int wave = threadIdx.x >> 6;
    const int lane = threadIdx.x & 63;
    const int row  = blockIdx.x * ROWS_PER_BLOCK + wave;
    if (row >= bs) return;

    // Row-uniform shift in atom-index space: idx_j = clip(j + s, 0, 50)
    const float r  = reward[row];
    const float s  = r * 2.5f;          // r / ATOM_DELTA, ATOM_DELTA = 0.4
    const float kf = floorf(s);
    const int   k  = (int)kf;
    const float f  = s - kf;            // fractional part in [0,1)

    // Each lane owns atom `lane` (lanes >= 51 hold 0)
    float p = 0.0f;
    if (lane < NUM_ATOMS) p = probs[(size_t)row * NUM_ATOMS + lane];

    // Clamp sums:
    //   low : atoms j with j + s < 0   -> all mass to bin 0
    //   high: atoms j with j + s > 50  -> all mass to bin 50
    float m_lo = ((float)lane + s < 0.0f)  ? p : 0.0f;
    float m_hi = ((float)lane + s > 50.0f) ? p : 0.0f;
    #pragma unroll
    for (int off = 32; off > 0; off >>= 1) {
        m_lo += __shfl_xor(m_lo, off, 64);
        m_hi += __shfl_xor(m_hi, off, 64);
    }

    // Interior gather for output bin i = lane:
    //   lower source j1 = i - k     (coef 1-f), valid if j1 in [0,51) and i+f <= 50
    //   upper source j2 = i - k - 1 (coef f),   valid if j2 in [0,51) and i-1+f >= 0
    const int   i  = lane;
    const int   j1 = i - k;
    const int   j2 = j1 - 1;
    const float p1 = __shfl(p, j1 & 63, 64);
    const float p2 = __shfl(p, j2 & 63, 64);

    const bool v1 = (j1 >= 0) && (j1 < NUM_ATOMS) && ((float)i + f <= 50.0f);
    const bool v2 = (j2 >= 0) && (j2 < NUM_ATOMS) && ((float)(i - 1) + f >= 0.0f);

    float o = 0.0f;
    if (v1) o += (1.0f - f) * p1;
    if (v2) o += f * p2;
    if (i == 0)             o += m_lo;
    if (i == NUM_ATOMS - 1) o += m_hi;

    if (i < NUM_ATOMS) out[(size_t)row * NUM_ATOMS + i] = o;
}

extern "C" void kernel_launch(void* const* d_in, const int* in_sizes, int n_in,
                              void* d_out, int out_size, void* d_ws, size_t ws_size,
                              hipStream_t stream) {
    const float* reward = (const float*)d_in[0];
    const float* probs  = (const float*)d_in[1];
    // d_in[2] = atom_values: unused — atom j sits exactly at index j in idx-space
    float* out = (float*)d_out;
    const int bs = in_sizes[0];

    const int blocks = (bs + ROWS_PER_BLOCK - 1) / ROWS_PER_BLOCK;
    c51_bellman_kernel<<<blocks, ROWS_PER_BLOCK * 64, 0, stream>>>(reward, probs, out, bs);
}

// Round 2
// 420.003 us; speedup vs baseline: 1.1184x; 1.1184x over previous
//
#include <hip/hip_runtime.h>

#define NA 51          // atoms
#define ROWS 256       // rows per block == threads per block
#define STRIDE 53      // [sentinel0][51 data][sentinel0] per row in LDS

// C51 Bellman projection, thread-per-row.
// Row-uniform shift s = reward*2.5, k=floor(s), f=frac(s):
//   out[i] = (1-f)*p[i-k]*[valid] + f*p[i-k-1]*[valid] + (i==0)*m_lo + (i==50)*m_hi
// m_lo = sum p[j] over j+s<0 (clamped low), m_hi = sum p[j] over j+s>50.
__global__ __launch_bounds__(256, 1) void c51_bellman_kernel(
    const float* __restrict__ reward,
    const float* __restrict__ probs,
    float* __restrict__ out,
    int bs)
{
    __shared__ float lds[ROWS * STRIDE];   // 53 KB -> 3 blocks/CU
    const int tid  = threadIdx.x;
    const int row0 = blockIdx.x * ROWS;
    const int nrows = min(ROWS, bs - row0);
    const int nelem = nrows * NA;
    const int n4    = nelem >> 2;

    // ---- zero sentinels for my row ----
    if (tid < nrows) {
        lds[tid * STRIDE]          = 0.0f;
        lds[tid * STRIDE + NA + 1] = 0.0f;
    }

    // ---- stage probs: coalesced float4 global loads -> scattered LDS writes ----
    const float4* p4 = (const float4*)(probs + (size_t)row0 * NA); // 16B aligned: 256*51*4 % 16 == 0
    for (int e4 = tid; e4 < n4; e4 += ROWS) {
        float4 v = p4[e4];
        unsigned g = (unsigned)e4 * 4u;
        unsigned r0 = g / 51u, j0 = g - r0 * 51u;
        // 4 consecutive flat elements; rows may advance across the quad
        float vv[4] = {v.x, v.y, v.z, v.w};
        #pragma unroll
        for (int c = 0; c < 4; ++c) {
            unsigned r = r0, j = j0 + c;
            if (j >= 51u) { j -= 51u; r += 1u; }   // at most one row crossing per quad
            lds[r * STRIDE + 1 + j] = vv[c];
        }
    }
    // scalar tail (nelem not multiple of 4 — not hit for bs=1e6 but keep correct)
    for (int e = (n4 << 2) + tid; e < nelem; e += ROWS) {
        unsigned r = (unsigned)e / 51u, j = (unsigned)e - r * 51u;
        lds[r * STRIDE + 1 + j] = probs[(size_t)row0 * NA + e];
    }
    __syncthreads();

    // ---- per-thread row compute ----
    const bool active = (tid < nrows);
    float* rp = &lds[tid * STRIDE + 1];   // rp[j]=p[j], rp[-1]=rp[51]=0
    if (active) {
        const float s  = reward[row0 + tid] * 2.5f;  // r / 0.4
        const float kf = floorf(s);
        const int   k  = (int)kf;
        const float f  = s - kf;

        // pass A: clamp masses (must finish before in-place overwrite)
        float m_lo = 0.0f, m_hi = 0.0f;
        #pragma unroll
        for (int j = 0; j < NA; ++j) {
            const float pj = rp[j];
            const float t  = (float)j + s;
            if (t < 0.0f)  m_lo += pj;
            if (t > 50.0f) m_hi += pj;
        }

        // pass B: gather + in-place write. Direction avoids read-after-write
        // clobber: k>=0 reads slots <= i+? below i -> sweep downward; k<0 upward.
        const bool down = (k >= 0);
        #pragma unroll
        for (int m = 0; m < NA; ++m) {
            const int i  = down ? (NA - 1 - m) : m;
            const int j2 = i - k - 1;          // upper-source atom
            const int j1 = j2 + 1;             // lower-source atom
            const int c  = min(max(j2, -1), NA - 1);  // clamp into sentinel range
            const float plo = rp[c];           // p[j2] when valid (else sentinel/masked)
            const float phi = rp[c + 1];       // p[j1] when valid
            float o = 0.0f;
            if (j1 >= 0 && j1 < NA && ((float)i + f) <= 50.0f)
                o += (1.0f - f) * phi;
            if (j2 >= 0 && j2 < NA && ((float)(i - 1) + f) >= 0.0f)
                o += f * plo;
            if (i == 0)      o += m_lo;
            if (i == NA - 1) o += m_hi;
            rp[i] = o;
        }
    }
    __syncthreads();

    // ---- copy-out: LDS -> coalesced float4 global stores ----
    float4* o4 = (float4*)(out + (size_t)row0 * NA);
    for (int e4 = tid; e4 < n4; e4 += ROWS) {
        unsigned g = (unsigned)e4 * 4u;
        unsigned r0 = g / 51u, j0 = g - r0 * 51u;
        float vv[4];
        #pragma unroll
        for (int c = 0; c < 4; ++c) {
            unsigned r = r0, j = j0 + c;
            if (j >= 51u) { j -= 51u; r += 1u; }
            vv[c] = lds[r * STRIDE + 1 + j];
        }
        float4 v; v.x = vv[0]; v.y = vv[1]; v.z = vv[2]; v.w = vv[3];
        o4[e4] = v;
    }
    for (int e = (n4 << 2) + tid; e < nelem; e += ROWS) {
        unsigned r = (unsigned)e / 51u, j = (unsigned)e - r * 51u;
        out[(size_t)row0 * NA + e] = lds[r * STRIDE + 1 + j];
    }
}

extern "C" void kernel_launch(void* const* d_in, const int* in_sizes, int n_in,
                              void* d_out, int out_size, void* d_ws, size_t ws_size,
                              hipStream_t stream) {
    const float* reward = (const float*)d_in[0];
    const float* probs  = (const float*)d_in[1];
    // d_in[2] = atom_values: unused — atom j sits exactly at index j in idx-space
    float* out = (float*)d_out;
    const int bs = in_sizes[0];

    const int blocks = (bs + ROWS - 1) / ROWS;
    c51_bellman_kernel<<<blocks, ROWS, 0, stream>>>(reward, probs, out, bs);
}